// Round 5
// baseline (230.808 us; speedup 1.0000x reference)
//
#include <hip/hip_runtime.h>
#include <math.h>

#define FDIM 128
#define CDIM 40

// ---------------------------------------------------------------------------
// Graph preprocessing
// ---------------------------------------------------------------------------

__global__ void k_init(int* __restrict__ deg, int n) {
    int i = blockIdx.x * blockDim.x + threadIdx.x;
    if (i < n) deg[i] = 0;
}

// Count degrees, 4 edges/thread (int4). The atomic's return value is each
// edge's rank within its dst (coalesced store) -> atomic-free fill later.
__global__ void k_count(const int* __restrict__ dst, int* __restrict__ deg,
                        int* __restrict__ pos_within, int e) {
    int i = blockIdx.x * blockDim.x + threadIdx.x;
    int i4 = i * 4;
    if (i4 + 3 < e) {
        int4 d = ((const int4*)dst)[i];
        int4 p;
        p.x = atomicAdd(&deg[d.x], 1);
        p.y = atomicAdd(&deg[d.y], 1);
        p.z = atomicAdd(&deg[d.z], 1);
        p.w = atomicAdd(&deg[d.w], 1);
        ((int4*)pos_within)[i] = p;
    } else if (i4 < e) {
        for (int k = i4; k < e; ++k)
            pos_within[k] = atomicAdd(&deg[dst[k]], 1);
    }
}

// Single-block exclusive scan (n <= 16384): 16 items/thread serial prefix,
// wave shuffle-scan, cross-wave LDS combine. Also emits dinv = rsqrt(deg+1).
__global__ __launch_bounds__(1024) void k_scan(const int* __restrict__ deg,
                                               int* __restrict__ row_ptr,
                                               float* __restrict__ dinv, int n) {
    int tid = threadIdx.x;
    int base = tid * 16;
    int vals[16];
    int sum = 0;
    #pragma unroll
    for (int k = 0; k < 16; ++k) {
        int i = base + k;
        int v = (i < n) ? deg[i] : 0;
        vals[k] = sum;
        sum += v;
        if (i < n) dinv[i] = rsqrtf((float)(v + 1));
    }
    int lane = tid & 63;
    int wave = tid >> 6;
    int x = sum;
    #pragma unroll
    for (int off = 1; off < 64; off <<= 1) {
        int y = __shfl_up(x, off);
        if (lane >= off) x += y;
    }
    __shared__ int wsum[16];
    if (lane == 63) wsum[wave] = x;
    __syncthreads();
    if (wave == 0) {
        int w = (lane < 16) ? wsum[lane] : 0;
        #pragma unroll
        for (int off = 1; off < 16; off <<= 1) {
            int y = __shfl_up(w, off);
            if (lane >= off) w += y;
        }
        if (lane < 16) wsum[lane] = w;
    }
    __syncthreads();
    int wave_off = (wave > 0) ? wsum[wave - 1] : 0;
    int thread_excl = wave_off + x - sum;
    #pragma unroll
    for (int k = 0; k < 16; ++k) {
        int i = base + k;
        if (i < n) row_ptr[i] = thread_excl + vals[k];
    }
    if (tid == 1023) row_ptr[n] = wave_off + x;
}

// ---------------------------------------------------------------------------
// Mega kernel: blocks [0, gemm_blocks) = layer-1 GEMM (out = dinv*(A@W));
// remaining blocks = atomic-free CSR fill, 4 edges/thread.
// ---------------------------------------------------------------------------
__global__ __launch_bounds__(256) void k_mega(
        const float* __restrict__ A, const float* __restrict__ W,
        const float* __restrict__ dinv, float* __restrict__ out, int n,
        const int* __restrict__ src, const int* __restrict__ dst,
        const int* __restrict__ row_ptr, const int* __restrict__ pos_within,
        int* __restrict__ col_src, int e, int gemm_blocks) {
    __shared__ float As[32][FDIM];
    int tid = threadIdx.x;
    if ((int)blockIdx.x < gemm_blocks) {
        int r0 = blockIdx.x * 32;
        for (int t = tid; t < 32 * 32; t += 256) {
            int r = t >> 5, c4 = t & 31;
            int gr = r0 + r;
            float4 v = make_float4(0.f, 0.f, 0.f, 0.f);
            if (gr < n) v = ((const float4*)A)[(size_t)gr * 32 + c4];
            ((float4*)As[r])[c4] = v;
        }
        __syncthreads();
        int cb = (tid & 31) * 4;
        int rb = (tid >> 5) * 4;
        float4 acc0 = make_float4(0,0,0,0), acc1 = acc0, acc2 = acc0, acc3 = acc0;
        for (int k = 0; k < FDIM; ++k) {
            float4 w = *(const float4*)(W + k * FDIM + cb);
            float a0 = As[rb + 0][k], a1 = As[rb + 1][k];
            float a2 = As[rb + 2][k], a3 = As[rb + 3][k];
            acc0.x += a0 * w.x; acc0.y += a0 * w.y; acc0.z += a0 * w.z; acc0.w += a0 * w.w;
            acc1.x += a1 * w.x; acc1.y += a1 * w.y; acc1.z += a1 * w.z; acc1.w += a1 * w.w;
            acc2.x += a2 * w.x; acc2.y += a2 * w.y; acc2.z += a2 * w.z; acc2.w += a2 * w.w;
            acc3.x += a3 * w.x; acc3.y += a3 * w.y; acc3.z += a3 * w.z; acc3.w += a3 * w.w;
        }
        float4 accs[4] = {acc0, acc1, acc2, acc3};
        for (int i = 0; i < 4; ++i) {
            int gr = r0 + rb + i;
            if (gr < n) {
                float s = dinv[gr];
                float4 v = accs[i];
                v.x *= s; v.y *= s; v.z *= s; v.w *= s;
                ((float4*)out)[(size_t)gr * 32 + (cb >> 2)] = v;
            }
        }
    } else {
        int i = ((int)blockIdx.x - gemm_blocks) * 256 + tid;
        int i4 = i * 4;
        if (i4 + 3 < e) {
            int4 d = ((const int4*)dst)[i];
            int4 s = ((const int4*)src)[i];
            int4 p = ((const int4*)pos_within)[i];
            col_src[row_ptr[d.x] + p.x] = s.x;
            col_src[row_ptr[d.y] + p.y] = s.y;
            col_src[row_ptr[d.z] + p.z] = s.z;
            col_src[row_ptr[d.w] + p.w] = s.w;
        } else if (i4 < e) {
            for (int k = i4; k < e; ++k)
                col_src[row_ptr[dst[k]] + pos_within[k]] = src[k];
        }
    }
}

// ---------------------------------------------------------------------------
// Wave-per-node aggregation: the two 32-lane halves of a wave each gather
// half the neighbor list (float4/lane over 128 feats), combined with
// __shfl_xor(.,32). Result (bias applied, optional ReLU) is written to this
// wave's private LDS row slot. No __syncthreads anywhere.
// ---------------------------------------------------------------------------
template <bool RELU>
__device__ __forceinline__ void wave_agg_row(
        float* __restrict__ lds_row, const float4* __restrict__ hs4,
        const float* __restrict__ dinv, const int* __restrict__ row_ptr,
        const int* __restrict__ col_src, const float4* __restrict__ bias4,
        int node, int lane) {
    int half = lane >> 5;
    int l32 = lane & 31;
    int beg = row_ptr[node], end = row_ptr[node + 1];
    int degn = end - beg;
    int mid = beg + (degn >> 1);
    int jb = half ? mid : beg;
    int je = half ? end : mid;
    float4 acc0 = make_float4(0.f, 0.f, 0.f, 0.f);
    float4 acc1 = acc0;
    if (half == 0) acc0 = hs4[(size_t)node * 32 + l32];   // self-loop term
    int j = jb;
    for (; j + 8 <= je; j += 8) {
        int s0 = col_src[j + 0], s1 = col_src[j + 1];
        int s2 = col_src[j + 2], s3 = col_src[j + 3];
        int s4 = col_src[j + 4], s5 = col_src[j + 5];
        int s6 = col_src[j + 6], s7 = col_src[j + 7];
        float4 a0 = hs4[(size_t)s0 * 32 + l32];
        float4 a1 = hs4[(size_t)s1 * 32 + l32];
        float4 a2 = hs4[(size_t)s2 * 32 + l32];
        float4 a3 = hs4[(size_t)s3 * 32 + l32];
        float4 a4 = hs4[(size_t)s4 * 32 + l32];
        float4 a5 = hs4[(size_t)s5 * 32 + l32];
        float4 a6 = hs4[(size_t)s6 * 32 + l32];
        float4 a7 = hs4[(size_t)s7 * 32 + l32];
        acc0.x += (a0.x + a2.x) + (a4.x + a6.x);
        acc0.y += (a0.y + a2.y) + (a4.y + a6.y);
        acc0.z += (a0.z + a2.z) + (a4.z + a6.z);
        acc0.w += (a0.w + a2.w) + (a4.w + a6.w);
        acc1.x += (a1.x + a3.x) + (a5.x + a7.x);
        acc1.y += (a1.y + a3.y) + (a5.y + a7.y);
        acc1.z += (a1.z + a3.z) + (a5.z + a7.z);
        acc1.w += (a1.w + a3.w) + (a5.w + a7.w);
    }
    for (; j < je; ++j) {
        float4 a = hs4[(size_t)col_src[j] * 32 + l32];
        acc0.x += a.x; acc0.y += a.y; acc0.z += a.z; acc0.w += a.w;
    }
    float4 acc;
    acc.x = acc0.x + acc1.x; acc.y = acc0.y + acc1.y;
    acc.z = acc0.z + acc1.z; acc.w = acc0.w + acc1.w;
    // combine the two halves (lane ^ 32)
    acc.x += __shfl_xor(acc.x, 32);
    acc.y += __shfl_xor(acc.y, 32);
    acc.z += __shfl_xor(acc.z, 32);
    acc.w += __shfl_xor(acc.w, 32);
    float di = dinv[node];
    float4 b = bias4[l32];
    float4 v;
    v.x = di * acc.x + b.x; v.y = di * acc.y + b.y;
    v.z = di * acc.z + b.z; v.w = di * acc.w + b.w;
    if (RELU) {
        v.x = fmaxf(v.x, 0.f); v.y = fmaxf(v.y, 0.f);
        v.z = fmaxf(v.z, 0.f); v.w = fmaxf(v.w, 0.f);
    }
    if (half == 0) ((float4*)lds_row)[l32] = v;
}

// ---------------------------------------------------------------------------
// Fused: agg1(+b1, ReLU) -> row @ W2 -> dinv scale -> out. 1 node per wave,
// 4 waves/block, no barriers. Each lane computes 2 output cols (float2).
// ---------------------------------------------------------------------------
__global__ __launch_bounds__(256) void k_agg_gemm(
        const float4* __restrict__ hs4, const float* __restrict__ dinv,
        const int* __restrict__ row_ptr, const int* __restrict__ col_src,
        const float4* __restrict__ bias4, const float* __restrict__ W2,
        float* __restrict__ out, int n) {
    __shared__ float rows[4][FDIM];   // 2 KB, one slot per wave
    int tid = threadIdx.x;
    int widx = tid >> 6, lane = tid & 63;
    int node = blockIdx.x * 4 + widx;
    if (node >= n) return;
    float* row = rows[widx];
    wave_agg_row<true>(row, hs4, dinv, row_ptr, col_src, bias4, node, lane);
    const float2* W2_2 = (const float2*)W2;
    float ax = 0.f, ay = 0.f;
    for (int k = 0; k < FDIM; k += 4) {
        float a0 = row[k + 0], a1 = row[k + 1];
        float a2 = row[k + 2], a3 = row[k + 3];
        float2 w0 = W2_2[(size_t)(k + 0) * 64 + lane];
        float2 w1 = W2_2[(size_t)(k + 1) * 64 + lane];
        float2 w2 = W2_2[(size_t)(k + 2) * 64 + lane];
        float2 w3 = W2_2[(size_t)(k + 3) * 64 + lane];
        ax += a0 * w0.x + a1 * w1.x + a2 * w2.x + a3 * w3.x;
        ay += a0 * w0.y + a1 * w1.y + a2 * w2.y + a3 * w3.y;
    }
    float di = dinv[node];
    float2 v; v.x = di * ax; v.y = di * ay;
    ((float2*)out)[(size_t)node * 64 + lane] = v;
}

// ---------------------------------------------------------------------------
// Fused: agg2(+b2) -> classifier (@Wc + bc) -> log_softmax -> out.
// 1 node per wave; lanes 0..39 compute the 40 logits.
// ---------------------------------------------------------------------------
__global__ __launch_bounds__(256) void k_agg_cls(
        const float4* __restrict__ hs4, const float* __restrict__ dinv,
        const int* __restrict__ row_ptr, const int* __restrict__ col_src,
        const float4* __restrict__ bias4, const float* __restrict__ Wc,
        const float* __restrict__ bc, float* __restrict__ out, int n) {
    __shared__ float rows[4][FDIM];   // 2 KB
    int tid = threadIdx.x;
    int widx = tid >> 6, lane = tid & 63;
    int node = blockIdx.x * 4 + widx;
    if (node >= n) return;
    float* row = rows[widx];
    wave_agg_row<false>(row, hs4, dinv, row_ptr, col_src, bias4, node, lane);
    float acc = 0.0f;
    if (lane < CDIM) {
        acc = bc[lane];
        for (int k = 0; k < FDIM; k += 4) {
            float a0 = row[k + 0], a1 = row[k + 1];
            float a2 = row[k + 2], a3 = row[k + 3];
            acc += a0 * Wc[(k + 0) * CDIM + lane];
            acc += a1 * Wc[(k + 1) * CDIM + lane];
            acc += a2 * Wc[(k + 2) * CDIM + lane];
            acc += a3 * Wc[(k + 3) * CDIM + lane];
        }
    }
    float v = (lane < CDIM) ? acc : -INFINITY;
    float m = v;
    for (int off = 32; off > 0; off >>= 1) m = fmaxf(m, __shfl_down(m, off));
    m = __shfl(m, 0);
    float e = (lane < CDIM) ? expf(v - m) : 0.0f;
    float s = e;
    for (int off = 32; off > 0; off >>= 1) s += __shfl_down(s, off);
    s = __shfl(s, 0);
    if (lane < CDIM) out[(size_t)node * CDIM + lane] = v - m - logf(s);
}

// ---------------------------------------------------------------------------

extern "C" void kernel_launch(void* const* d_in, const int* in_sizes, int n_in,
                              void* d_out, int out_size, void* d_ws, size_t ws_size,
                              hipStream_t stream) {
    const float* x  = (const float*)d_in[0];
    const int*   ei = (const int*)d_in[1];
    const float* W1 = (const float*)d_in[2];
    const float* b1 = (const float*)d_in[3];
    const float* W2 = (const float*)d_in[4];
    const float* b2 = (const float*)d_in[5];
    const float* Wc = (const float*)d_in[6];
    const float* bc = (const float*)d_in[7];
    float* out = (float*)d_out;

    const int N = in_sizes[0] / FDIM;
    const int E = in_sizes[1] / 2;
    const int* srcp = ei;         // edge_index[0]
    const int* dstp = ei + E;     // edge_index[1]

    char* ws = (char*)d_ws;
    auto alloc = [&](size_t bytes) {
        char* p = ws;
        ws += (bytes + 255) & ~(size_t)255;
        return p;
    };
    int*   deg        = (int*)  alloc((size_t)N * 4);
    int*   row_ptr    = (int*)  alloc((size_t)(N + 1) * 4);
    float* dinv       = (float*)alloc((size_t)N * 4);
    int*   pos_within = (int*)  alloc((size_t)E * 4);
    int*   col_src    = (int*)  alloc((size_t)E * 4);
    float* hbuf       = (float*)alloc((size_t)N * FDIM * 4);
    float* hbuf2      = (float*)alloc((size_t)N * FDIM * 4);

    // Graph build
    k_init <<<(N + 255) / 256, 256, 0, stream>>>(deg, N);
    k_count<<<(E / 4 + 256) / 256, 256, 0, stream>>>(dstp, deg, pos_within, E);
    k_scan <<<1, 1024, 0, stream>>>(deg, row_ptr, dinv, N);

    // Layer-1 GEMM fused with CSR fill
    int gemm_blocks = (N + 31) / 32;
    int fill_blocks = (E / 4 + 256) / 256;
    k_mega<<<gemm_blocks + fill_blocks, 256, 0, stream>>>(
        x, W1, dinv, hbuf, N, srcp, dstp, row_ptr, pos_within, col_src, E,
        gemm_blocks);

    // agg1(+relu) -> @W2 -> hs2   (wave per node)
    k_agg_gemm<<<(N + 3) / 4, 256, 0, stream>>>(
        (const float4*)hbuf, dinv, row_ptr, col_src, (const float4*)b1, W2,
        hbuf2, N);

    // agg2 -> classifier -> log_softmax   (wave per node)
    k_agg_cls<<<(N + 3) / 4, 256, 0, stream>>>(
        (const float4*)hbuf2, dinv, row_ptr, col_src, (const float4*)b2, Wc,
        bc, out, N);
}